// Round 6
// baseline (559.722 us; speedup 1.0000x reference)
//
#include <hip/hip_runtime.h>

// Spatial LRN: out = x / (2 + 1e-4 * ssq)^0.75, ssq = 5x5 box sum of x^2 (zero pad 2).
// x: (16, 96, 224, 224) fp32.
//
// Round-6 = round-5 resubmitted (container infra failure, kernel never ran).
//
// R3's shuffle-free straight-line burst, shrunk to 2 output rows/job so
// occupancy (resident waves = in-flight bytes) goes up ~1.75x. Evidence:
// copy kernel does 6.3 TB/s mixed R+W at 32 waves/CU & 8 VGPR; R3 was stuck at
// ~50% occupancy with 36 load-dests batched under a 128-VGPR cap. Shuffle
// variants (R2/R4) regressed: DS round-trips in the arrival->fold path cost
// more than the xl/xr loads they remove (those are L1 hits).
//
// Per job (one wave, 2 output rows x 224 cols of one plane):
//   - issue all 6 xc loads first (the HBM-missing stream gets deep MLP,
//     24 VGPR of destinations),
//   - per row fold xl/xr (L1-hit loads) + hsum directly into 2 accumulators
//     (no rs[] array) -> ~60 live VGPR, __launch_bounds__(256,7) => 28 waves/CU.
//   - XCD-swizzled blockIdx: vertically-adjacent jobs share 4/6 input rows;
//     keep them on the same XCD's L2 (default round-robin scatters them).
// Lane q owns float4 column group q (56 active, 8 guard lanes mirror lane 55
// and never store). Jobs = 16*96 planes * 112 slabs = 172032 -> 43008 blocks.

typedef float f4 __attribute__((ext_vector_type(4)));

#define LRN_H 224
#define LRN_W 224
#define LRN_WQ 56                    // float4 groups per row
#define LRN_R 2                      // output rows per job
#define LRN_IN (LRN_R + 4)           // 6 input rows per job
#define LRN_SLABS (LRN_H / LRN_R)    // 112
#define LRN_PLANE (LRN_H * LRN_W)
#define LRN_BLOCKS 43008             // 172032 jobs / 4 waves
#define LRN_BPX (LRN_BLOCKS / 8)     // blocks per XCD chunk (bijective: %8==0)

__global__ __launch_bounds__(256, 7) void LocalResponseNorm_17420387352942_kernel(
        const float* __restrict__ x, float* __restrict__ out) {
    // Bijective XCD swizzle: consecutive job IDs (adjacent slabs, shared halo
    // rows) stay on one XCD's L2 instead of round-robining across 8.
    const int b    = blockIdx.x;
    const int swz  = (b & 7) * LRN_BPX + (b >> 3);
    const int q    = threadIdx.x & 63;
    const int wave = threadIdx.x >> 6;
    const int job  = swz * 4 + wave;               // [0, 172032)
    const int plane = job / LRN_SLABS;
    const int slab  = job - plane * LRN_SLABS;
    const int h0    = slab * LRN_R;                // first output row

    const int qe = min(q, LRN_WQ - 1);             // guard lanes mirror lane 55
    const float* __restrict__ px = x   + (size_t)plane * LRN_PLANE + (qe << 2);
    float* __restrict__       po = out + (size_t)plane * LRN_PLANE + (qe << 2);

    const float mL = (qe > 0)          ? 1.0f : 0.0f;
    const float mR = (qe < LRN_WQ - 1) ? 1.0f : 0.0f;
    const int offL = (qe > 0)          ? -4 : 0;   // clamped: stays in-bounds
    const int offR = (qe < LRN_WQ - 1) ?  4 : 0;
    const bool wr  = (q < LRN_WQ);

    // ---- Issue all 6 center loads first (rows h0-2 .. h0+3, clamped).
    f4 xc[LRN_IN];
#pragma unroll
    for (int r = 0; r < LRN_IN; ++r) {
        const int row = h0 + r - 2;
        const int rc  = min(max(row, 0), LRN_H - 1);
        xc[r] = *(const f4*)(px + rc * LRN_W);
    }

    // ---- Fold: per row, xl/xr (L1 hits) + 5-tap horizontal sum -> 2 accs.
    f4 acc0 = (f4){0.f, 0.f, 0.f, 0.f};
    f4 acc1 = (f4){0.f, 0.f, 0.f, 0.f};

#pragma unroll
    for (int r = 0; r < LRN_IN; ++r) {
        const int row = h0 + r - 2;
        const float mV = (row >= 0 && row < LRN_H) ? 1.0f : 0.0f;
        const int rc   = min(max(row, 0), LRN_H - 1);
        const float* rp = px + rc * LRN_W;
        f4 xl = *(const f4*)(rp + offL);
        f4 xr = *(const f4*)(rp + offR);

        float a  = xl[2] * xl[2] * mL;
        float bb = xl[3] * xl[3] * mL;
        float c0 = xc[r][0] * xc[r][0];
        float c1 = xc[r][1] * xc[r][1];
        float c2 = xc[r][2] * xc[r][2];
        float c3 = xc[r][3] * xc[r][3];
        float d0 = xr[0] * xr[0] * mR;
        float d1 = xr[1] * xr[1] * mR;
        float t  = c1 + c2;
        f4 rs;
        rs[0] = (a + bb + c0 + t) * mV;    // cols 4q-2 .. 4q+2
        rs[1] = (bb + c0 + t + c3) * mV;
        rs[2] = (c0 + t + c3 + d0) * mV;
        rs[3] = (t + c3 + d0 + d1) * mV;

        // out row h0 uses input rows r=0..4; out row h0+1 uses r=1..5.
        if (r <= 4) acc0 += rs;
        if (r >= 1) acc1 += rs;
    }

    // ---- Epilogue: d^-0.75 via rsq + sqrt(rsq); centers xc[2], xc[3].
    f4 o0, o1;
#pragma unroll
    for (int j = 0; j < 4; ++j) {
        float d0  = fmaf(1e-4f, acc0[j], 2.0f);
        float rs0 = __builtin_amdgcn_rsqf(d0);
        o0[j] = xc[2][j] * rs0 * __builtin_amdgcn_sqrtf(rs0);
        float d1  = fmaf(1e-4f, acc1[j], 2.0f);
        float rs1 = __builtin_amdgcn_rsqf(d1);
        o1[j] = xc[3][j] * rs1 * __builtin_amdgcn_sqrtf(rs1);
    }
    if (wr) {
        __builtin_nontemporal_store(o0, (f4*)(po + h0 * LRN_W));
        __builtin_nontemporal_store(o1, (f4*)(po + (h0 + 1) * LRN_W));
    }
}

extern "C" void kernel_launch(void* const* d_in, const int* in_sizes, int n_in,
                              void* d_out, int out_size, void* d_ws, size_t ws_size,
                              hipStream_t stream) {
    const float* x = (const float*)d_in[0];
    float* out = (float*)d_out;
    // 16*96 planes * 112 slabs = 172032 jobs; 4 waves per block -> 43008 blocks.
    dim3 block(256, 1, 1);
    dim3 grid(LRN_BLOCKS, 1, 1);
    LocalResponseNorm_17420387352942_kernel<<<grid, block, 0, stream>>>(x, out);
}

// Round 7
// 519.401 us; speedup vs baseline: 1.0776x; 1.0776x over previous
//
#include <hip/hip_runtime.h>

// Spatial LRN: out = x / (2 + 1e-4 * ssq)^0.75, ssq = 5x5 box sum of x^2 (zero pad 2).
// x: (16, 96, 224, 224) fp32.
//
// Round-7: R3 geometry (8 out rows / 12 in rows per wave-job, best measured
// ~166us) + two-stream load schedule. Evidence so far:
//   R3 (all 36 loads up front): xl/xr issue before their xc sibling returns ->
//       all miss L1, 3x L2 request traffic, batched drains. ~166us.
//   R6 (xc up front, xl/xr right before use): 6 serial L1-hit latencies/job,
//       793 cyc/job, 222us despite 85% occupancy. Occupancy lever falsified.
// Fix: xc[12] (the only HBM-missing stream) issues up front; xl/xr issue with
// a 2-row lookahead -- after xc made the line L1-resident, early enough to
// hide L1-hit latency under two fold bodies. Fold scatters into acc[8]
// directly; centers reuse live xc[2..9]. ~110 VGPR, launch_bounds(256,4).
//
// Lane q owns float4 column group q (56 active, 8 guard lanes mirror lane 55,
// never store). Jobs = 16*96 planes * 28 slabs = 43008 -> 10752 blocks.

typedef float f4 __attribute__((ext_vector_type(4)));

#define LRN_H 224
#define LRN_W 224
#define LRN_WQ 56                    // float4 groups per row
#define LRN_R 8                      // output rows per job
#define LRN_IN (LRN_R + 4)           // 12 input rows per job
#define LRN_SLABS (LRN_H / LRN_R)    // 28
#define LRN_PLANE (LRN_H * LRN_W)
#define LRN_BLOCKS 10752             // 43008 jobs / 4 waves
#define LRN_BPX (LRN_BLOCKS / 8)     // bijective XCD chunk (10752 % 8 == 0)

__global__ __launch_bounds__(256, 4) void LocalResponseNorm_17420387352942_kernel(
        const float* __restrict__ x, float* __restrict__ out) {
    // Bijective XCD swizzle: vertically-adjacent jobs (shared halo rows) stay
    // on one XCD's L2.
    const int b    = blockIdx.x;
    const int swz  = (b & 7) * LRN_BPX + (b >> 3);
    const int q    = threadIdx.x & 63;
    const int wave = threadIdx.x >> 6;
    const int job  = swz * 4 + wave;               // [0, 43008)
    const int plane = job / LRN_SLABS;
    const int slab  = job - plane * LRN_SLABS;
    const int h0    = slab * LRN_R;                // first output row

    const int qe = min(q, LRN_WQ - 1);             // guard lanes mirror lane 55
    const float* __restrict__ px = x   + (size_t)plane * LRN_PLANE + (qe << 2);
    float* __restrict__       po = out + (size_t)plane * LRN_PLANE + (qe << 2);

    const float mL = (qe > 0)          ? 1.0f : 0.0f;
    const float mR = (qe < LRN_WQ - 1) ? 1.0f : 0.0f;
    const int offL = (qe > 0)          ? -4 : 0;   // clamped: stays in-bounds
    const int offR = (qe < LRN_WQ - 1) ?  4 : 0;
    const bool wr  = (q < LRN_WQ);

    // ---- Phase 1: the HBM-missing stream. All 12 center loads issue up front.
    f4 xc[LRN_IN];
#pragma unroll
    for (int r = 0; r < LRN_IN; ++r) {
        const int rc = min(max(h0 + r - 2, 0), LRN_H - 1);
        xc[r] = *(const f4*)(px + rc * LRN_W);
    }

    // ---- Phase 2 prologue: xl/xr of rows 0,1 (lines already requested by xc).
    f4 xlp[2], xrp[2];
#pragma unroll
    for (int r = 0; r < 2; ++r) {
        const int rc = min(max(h0 + r - 2, 0), LRN_H - 1);
        const float* rp = px + rc * LRN_W;
        xlp[r] = *(const f4*)(rp + offL);
        xrp[r] = *(const f4*)(rp + offR);
    }

    f4 acc[LRN_R];
#pragma unroll
    for (int i = 0; i < LRN_R; ++i) acc[i] = (f4){0.f, 0.f, 0.f, 0.f};

    // ---- Pipelined fold: consume xc in load order (fine-grained vmcnt);
    // xl/xr of row r+2 issue while folding row r (2-row lookahead, L1-hot).
#pragma unroll
    for (int r = 0; r < LRN_IN; ++r) {
        f4 xl = xlp[r & 1];
        f4 xr = xrp[r & 1];
        if (r + 2 < LRN_IN) {                      // refill just-consumed slot
            const int rc2 = min(max(h0 + r, 0), LRN_H - 1);  // row h0+(r+2)-2
            const float* rp2 = px + rc2 * LRN_W;
            xlp[r & 1] = *(const f4*)(rp2 + offL);
            xrp[r & 1] = *(const f4*)(rp2 + offR);
        }

        const int row = h0 + r - 2;
        const float mV = (r >= 2 && r < 10) ? 1.0f
                        : ((row >= 0 && row < LRN_H) ? 1.0f : 0.0f);

        float a  = xl[2] * xl[2] * mL;
        float bb = xl[3] * xl[3] * mL;
        float c0 = xc[r][0] * xc[r][0];
        float c1 = xc[r][1] * xc[r][1];
        float c2 = xc[r][2] * xc[r][2];
        float c3 = xc[r][3] * xc[r][3];
        float d0 = xr[0] * xr[0] * mR;
        float d1 = xr[1] * xr[1] * mR;
        float t  = c1 + c2;
        f4 rs;
        rs[0] = (a + bb + c0 + t) * mV;            // cols 4q-2 .. 4q+2
        rs[1] = (bb + c0 + t + c3) * mV;
        rs[2] = (c0 + t + c3 + d0) * mV;
        rs[3] = (t + c3 + d0 + d1) * mV;

        // rowsum of input row r feeds output rows i in [r-4, r] ∩ [0, 8).
#pragma unroll
        for (int i = 0; i < LRN_R; ++i) {
            if (i <= r && r <= i + 4) acc[i] += rs;
        }
    }

    // ---- Epilogue: d^-0.75 via rsq + sqrt(rsq); centers are the live xc[i+2].
#pragma unroll
    for (int i = 0; i < LRN_R; ++i) {
        f4 o;
#pragma unroll
        for (int j = 0; j < 4; ++j) {
            float d   = fmaf(1e-4f, acc[i][j], 2.0f);
            float rsq = __builtin_amdgcn_rsqf(d);                 // d^-0.5
            o[j] = xc[i + 2][j] * rsq * __builtin_amdgcn_sqrtf(rsq); // * d^-0.25
        }
        if (wr) __builtin_nontemporal_store(o, (f4*)(po + (h0 + i) * LRN_W));
    }
}

extern "C" void kernel_launch(void* const* d_in, const int* in_sizes, int n_in,
                              void* d_out, int out_size, void* d_ws, size_t ws_size,
                              hipStream_t stream) {
    const float* x = (const float*)d_in[0];
    float* out = (float*)d_out;
    // 16*96 planes * 28 slabs = 43008 jobs; 4 waves per block -> 10752 blocks.
    dim3 block(256, 1, 1);
    dim3 grid(LRN_BLOCKS, 1, 1);
    LocalResponseNorm_17420387352942_kernel<<<grid, block, 0, stream>>>(x, out);
}